// Round 6
// baseline (861.357 us; speedup 1.0000x reference)
//
// Round 6: flagless exchange — poll the data itself (poison = bf16 NaN-pair,
// unreachable by bounded h). 3-deep H ring, writer-side re-poison (ordering by
// transitive publish<=readback chain + one compute-shadowed vmcnt drain).
// l2-first schedule (h2 publish hidden under l1), hf reuse, LDS parity tiles,
// ONE __syncthreads per step; fc overlaps next step's compute.
#include <hip/hip_runtime.h>

typedef unsigned short u16;
typedef unsigned int   u32;
typedef unsigned long long u64;
typedef __attribute__((ext_vector_type(8))) short bf16x8;  // 8 bf16 (4 VGPRs)
typedef __attribute__((ext_vector_type(4))) float f32x4;   // MFMA C/D frag

#define DEVINL static __device__ __forceinline__
#define MFMA __builtin_amdgcn_mfma_f32_16x16x32_bf16
#define POISON32 0x7FFF7FFFu

DEVINL u16 f2bf(float f){ u32 x = __float_as_uint(f); return (u16)((x + 0x7fffu + ((x>>16)&1u)) >> 16); }
DEVINL float bf2f(u16 u){ return __uint_as_float(((u32)u) << 16); }
DEVINL u32 pack2(float a, float b){ return (u32)f2bf(a) | ((u32)f2bf(b) << 16); }
DEVINL float sigm(float x){ return 1.f/(1.f + __expf(-x)); }
DEVINL float tanhs(float x){ float xc = fminf(fmaxf(x,-15.f),15.f); float e = __expf(2.f*xc); return (e-1.f)/(e+1.f); }
DEVINL void g_store(u32* p, u32 v){ __hip_atomic_store(p, v, __ATOMIC_RELAXED, __HIP_MEMORY_SCOPE_AGENT); }
DEVINL u64  g_load64(const u64* p){ return __hip_atomic_load(p, __ATOMIC_RELAXED, __HIP_MEMORY_SCOPE_AGENT); }
DEVINL bool ok64(u64 v){ return ((u32)v != POISON32) && ((u32)(v >> 32) != POISON32); }

// ---------------- prep: pack weights bf16, rows permuted j' = u*4+gate; poison H ring
// matrix order m: 0 eIH_l0, 1 eHH_l0, 2 eIH_l1, 3 eHH_l1, 4 dIH_l0, 5 dHH_l0, 6 dIH_l1, 7 dHH_l1
__global__ void pack_all(const float* __restrict__ eih, const float* __restrict__ ehh,
                         const float* __restrict__ dih, const float* __restrict__ dhh,
                         const float* __restrict__ ebi, const float* __restrict__ ebh,
                         const float* __restrict__ dbi, const float* __restrict__ dbh,
                         u16* __restrict__ wout, float* __restrict__ bout,
                         u32* __restrict__ Hp){
  int blk = blockIdx.x, t = threadIdx.x;
  if (blk < 8192){
    int m = blk >> 10, j2 = blk & 1023;
    const float* base = (m < 4) ? ((m & 1) ? ehh : eih) : ((m & 1) ? dhh : dih);
    const float* S = base + (size_t)((m >> 1) & 1) * 262144;  // layer select
    int u = j2 >> 2, g = j2 & 3, j = g*256 + u;
    wout[(size_t)blk*256 + t] = f2bf(S[(size_t)j*256 + t]);
  } else if (blk < 8208){
    int idx = (blk - 8192)*256 + t;             // 0..4095 : [phase][layer][j']
    int phase = idx >> 11, l = (idx >> 10) & 1, j2 = idx & 1023;
    int u = j2 >> 2, g = j2 & 3, j = g*256 + u;
    const float* bi = phase ? dbi : ebi;
    const float* bh = phase ? dbh : ebh;
    bout[idx] = bi[l*1024 + j] + bh[l*1024 + j];
  } else {
    int idx = (blk - 8208)*256 + t;             // 0..393215: poison H1(3x32x2048)+H2
    Hp[idx] = POISON32;                          // re-poisoned EVERY call
  }
}

struct SM {
  u16   A1[2][16][520];   // [parity][row][ x 0..255 | h1 256..511 ]
  u16   A2[2][16][264];   // [parity][row][ h2 0..255 ]
  float fcw[4][256];
  float fcb[4];
  int   tok[63][16];
};

__global__ void __launch_bounds__(512, 2)
lstm_main(const int* __restrict__ src, const float* __restrict__ enc_emb,
          const float* __restrict__ dec_emb, const u16* __restrict__ wpack,
          const float* __restrict__ bpack, const float* __restrict__ fcW,
          const float* __restrict__ fcb, float* __restrict__ out,
          u32* __restrict__ H1, u32* __restrict__ H2)
{
  __shared__ SM sm;
  const int tid  = threadIdx.x;
  const int wv   = tid >> 6;          // wave 0..7
  const int lane = tid & 63;
  const int agrp = lane >> 4;         // k-group
  const int n    = lane & 15;         // batch row
  const int gid  = blockIdx.x & 31;   // batch group
  const int w    = blockIdx.x >> 5;   // column-slice 0..7
  const int wgb0 = gid << 4;
  const int xr   = tid >> 5, xc = (tid & 31) << 3;      // x-gather: row, col8
  const int jrow = (w << 7) + (wv << 4) + n;            // permuted gate row j'
  const int uu   = (w << 5) + (wv << 2) + agrp;         // unit owned by lane
  const int pw   = (w << 4) + (wv << 1) + (agrp >> 1);  // u32 word in H slice
  const bool pub = (agrp & 1) == 0;

  // ---- prologue staging
  for (int i = tid; i < 1008; i += 512){
    int s = i >> 4, b = i & 15;
    int t = (s < 31) ? (31 - s) : (s - 31);   // enc reversed, then dec forward
    sm.tok[s][b] = src[t*512 + wgb0 + b];
  }
  for (int i = tid; i < 1024; i += 512) ((float*)sm.fcw)[i] = fcW[i];
  if (tid < 4) sm.fcb[tid] = fcb[tid];
  { u32* z1 = (u32*)sm.A1; for (int i = tid; i < 8320; i += 512) z1[i] = 0u; }
  { u32* z2 = (u32*)sm.A2; for (int i = tid; i < 4224; i += 512) z2[i] = 0u; }
  __syncthreads();
  { // x(0) -> A1[0] lo
    int tk = sm.tok[0][xr];
    const float* e = enc_emb + (size_t)tk*256 + xc;
    float4 v0 = *(const float4*)e, v1 = *(const float4*)(e + 4);
    u32* d = (u32*)&sm.A1[0][xr][xc];
    d[0]=pack2(v0.x,v0.y); d[1]=pack2(v0.z,v0.w); d[2]=pack2(v1.x,v1.y); d[3]=pack2(v1.z,v1.w);
  }

  // ---- weight-stationary registers: W[2][16] (128 regs, unified VGPR/AGPR file)
  bf16x8 W[2][16];
  float4 br[2];
  float  c1 = 0.f, c2s = 0.f;

  auto LOADW_L = [&](int ph, int l){
    const u16* base = wpack + (size_t)ph * 1048576;
    #pragma unroll
    for (int kk = 0; kk < 16; kk++){
      const u16* mp = base + (size_t)((l << 1) + (kk >> 3))*262144
                    + (size_t)jrow*256 + ((kk & 7) << 5) + (agrp << 3);
      W[l][kk] = *(const bf16x8*)mp;
    }
    br[l] = *(const float4*)(bpack + (((ph << 1) + l) << 10) + (uu << 2));
  };
  LOADW_L(0, 0); LOADW_L(0, 1);
  __syncthreads();

  auto step = [&](int t, bool doA){
    const int parR = t & 1, parW = parR ^ 1;
    // ---- issue x(t+1) loads + writer-side poisons (drained before publish)
    const bool hasx = doA && (t + 1) < 63;
    float4 xv0, xv1;
    if (hasx){
      int tk = sm.tok[t+1][xr];
      const float* e = ((t+1) < 31 ? enc_emb : dec_emb) + (size_t)tk*256 + xc;
      xv0 = *(const float4*)e; xv1 = *(const float4*)(e + 4);
    }
    if (doA && pub){
      g_store(H1 + ((size_t)((t + 1) % 3)*32 + gid)*2048 + n*128 + pw, POISON32);
      g_store(H2 + ((size_t)(t % 3)*32 + gid)*2048 + n*128 + pw, POISON32);
    }
    // ---- hf = h1(t-1) fragments (feed BOTH l2 k-lo and l1 k-hi)
    bf16x8 hf[8];
    #pragma unroll
    for (int kk = 0; kk < 8; kk++)
      hf[kk] = *(const bf16x8*)&sm.A1[parR][n][256 + (kk << 5) + (agrp << 3)];
    // ---- phase B first: l2(t-1); its h2 publish latency hides under phase A
    if (t > 0){
      f32x4 a2 = {0.f,0.f,0.f,0.f};
      #pragma unroll
      for (int kk = 0; kk < 8; kk++)
        a2 = MFMA(W[1][kk], hf[kk], a2, 0, 0, 0);
      #pragma unroll
      for (int kk = 0; kk < 8; kk++){
        bf16x8 b2 = *(const bf16x8*)&sm.A2[parR][n][(kk << 5) + (agrp << 3)];
        a2 = MFMA(W[1][8 + kk], b2, a2, 0, 0, 0);
      }
      float I = sigm(a2[0] + br[1].x), F = sigm(a2[1] + br[1].y);
      float G = tanhs(a2[2] + br[1].z), O = sigm(a2[3] + br[1].w);
      float cn = F*c2s + I*G; c2s = cn;
      u16 hb = f2bf(O * tanhs(cn));
      u32 other = (u32)__shfl_xor((int)(u32)hb, 16);
      asm volatile("s_waitcnt vmcnt(0)" ::: "memory");   // poisons (+x) landed
      if (pub)
        g_store(H2 + ((size_t)((t - 1) % 3)*32 + gid)*2048 + n*128 + pw,
                (u32)hb | (other << 16));
    } else {
      asm volatile("s_waitcnt vmcnt(0)" ::: "memory");
    }
    // ---- phase A: l1(t) over [x(t); h1(t-1)]
    if (doA){
      f32x4 a1 = {0.f,0.f,0.f,0.f};
      #pragma unroll
      for (int kk = 0; kk < 8; kk++){
        bf16x8 bx = *(const bf16x8*)&sm.A1[parR][n][(kk << 5) + (agrp << 3)];
        a1 = MFMA(W[0][kk], bx, a1, 0, 0, 0);
      }
      #pragma unroll
      for (int kk = 0; kk < 8; kk++)
        a1 = MFMA(W[0][8 + kk], hf[kk], a1, 0, 0, 0);
      float I = sigm(a1[0] + br[0].x), F = sigm(a1[1] + br[0].y);
      float G = tanhs(a1[2] + br[0].z), O = sigm(a1[3] + br[0].w);
      float cn = F*c1 + I*G; c1 = cn;
      u16 hb = f2bf(O * tanhs(cn));
      u32 other = (u32)__shfl_xor((int)(u32)hb, 16);
      if (pub)
        g_store(H1 + ((size_t)(t % 3)*32 + gid)*2048 + n*128 + pw,
                (u32)hb | (other << 16));
    }
    asm volatile("" ::: "memory");
    // ---- poll-readback: each thread polls ITS OWN 4+4 words (detect == read)
    const int q2 = tid << 1;                       // u64 index (4 u32 = 2 u64)
    u64 A = 0, B = 0, C = 0, D = 0;
    if (doA){
      const u64* b1 = (const u64*)(H1 + ((size_t)(t % 3)*32 + gid)*2048);
      for (;;){
        A = g_load64(b1 + q2); B = g_load64(b1 + q2 + 1);
        if (ok64(A) && ok64(B)) break;
        __builtin_amdgcn_s_sleep(1);
      }
    }
    if (t > 0){
      const u64* b2 = (const u64*)(H2 + ((size_t)((t - 1) % 3)*32 + gid)*2048);
      for (;;){
        C = g_load64(b2 + q2); D = g_load64(b2 + q2 + 1);
        if (ok64(C) && ok64(D)) break;
        __builtin_amdgcn_s_sleep(1);
      }
    }
    // ---- LDS writes to parity parW
    const int r = tid >> 5, p2 = (tid & 31) << 2;  // row, first u32-word-in-row
    if (doA){
      u32* d1 = (u32*)&sm.A1[parW][r][256 + (p2 << 1)];
      d1[0] = (u32)A; d1[1] = (u32)(A >> 32); d1[2] = (u32)B; d1[3] = (u32)(B >> 32);
    }
    if (t > 0){
      u32* d2 = (u32*)&sm.A2[parW][r][p2 << 1];
      d2[0] = (u32)C; d2[1] = (u32)(C >> 32); d2[2] = (u32)D; d2[3] = (u32)(D >> 32);
    }
    if (hasx){
      u32* d = (u32*)&sm.A1[parW][xr][xc];
      d[0]=pack2(xv0.x,xv0.y); d[1]=pack2(xv0.z,xv0.w);
      d[2]=pack2(xv1.x,xv1.y); d[3]=pack2(xv1.z,xv1.w);
    }
    __syncthreads();                               // the ONLY barrier per step
    // ---- fc + log_softmax on h2(t-1) in A2[parW]; overlaps next step's compute
    if (t >= 32 && tid < 128){
      const int b = (w << 1) + (tid >> 6), v = (tid >> 4) & 3, q16 = tid & 15;
      const u16* hrow = &sm.A2[parW][b][q16 << 4];
      const float* wr = &sm.fcw[v][q16 << 4];
      bf16x8 h0 = *(const bf16x8*)hrow, h1v = *(const bf16x8*)(hrow + 8);
      float s = 0.f;
      #pragma unroll
      for (int e = 0; e < 8; e++){
        s += bf2f((u16)h0[e]) * wr[e];
        s += bf2f((u16)h1v[e]) * wr[8 + e];
      }
      s += __shfl_xor(s, 1); s += __shfl_xor(s, 2);
      s += __shfl_xor(s, 4); s += __shfl_xor(s, 8);
      s += sm.fcb[v];
      float m = fmaxf(s, __shfl_xor(s, 16)); m = fmaxf(m, __shfl_xor(m, 32));
      float e_ = __expf(s - m);
      float es = e_ + __shfl_xor(e_, 16); es += __shfl_xor(es, 32);
      if (q16 == 0)
        out[((size_t)(t - 32)*512 + wgb0 + b)*4 + v] = s - m - __logf(es);
    }
  };

  for (int t = 0; t <= 30; ++t) step(t, true);
  LOADW_L(1, 0);            // dec W1 (first used by l1(31)); l2(30) still enc W2
  step(31, true);
  LOADW_L(1, 1);            // dec W2 (first used by l2(31) at step 32)
  for (int t = 32; t <= 62; ++t) step(t, true);
  step(63, false);          // tail: l2(62) + fc(62) -> out row 31
}

extern "C" void kernel_launch(void* const* d_in, const int* in_sizes, int n_in,
                              void* d_out, int out_size, void* d_ws, size_t ws_size,
                              hipStream_t stream){
  const int*   src     = (const int*)  d_in[0];
  const float* enc_emb = (const float*)d_in[2];
  const float* enc_Wih = (const float*)d_in[3];
  const float* enc_Whh = (const float*)d_in[4];
  const float* enc_bih = (const float*)d_in[5];
  const float* enc_bhh = (const float*)d_in[6];
  const float* dec_emb = (const float*)d_in[7];
  const float* dec_Wih = (const float*)d_in[8];
  const float* dec_Whh = (const float*)d_in[9];
  const float* dec_bih = (const float*)d_in[10];
  const float* dec_bhh = (const float*)d_in[11];
  const float* fcW     = (const float*)d_in[12];
  const float* fcb     = (const float*)d_in[13];
  float* out = (float*)d_out;
  (void)in_sizes; (void)n_in; (void)out_size; (void)ws_size;

  // ws: wpack 4MB | bpack 16KB | H1 768KB (3-deep) | H2 768KB   (~5.5MB)
  u16*   wpack = (u16*)d_ws;
  float* bpack = (float*)((char*)d_ws + 4194304);
  u32*   H1    = (u32*)((char*)d_ws + 4194304 + 16384);
  u32*   H2    = H1 + 196608;

  pack_all<<<9744, 256, 0, stream>>>(enc_Wih, enc_Whh, dec_Wih, dec_Whh,
                                     enc_bih, enc_bhh, dec_bih, dec_bhh,
                                     wpack, bpack, H1);
  lstm_main<<<256, 512, 0, stream>>>(src, enc_emb, dec_emb, wpack, bpack,
                                     fcW, fcb, out, H1, H2);
}

// Round 7
// 689.775 us; speedup vs baseline: 1.2488x; 1.2488x over previous
//
// Round 7: round-4 skeleton + 4 surgical fixes.
// (1) coalesced H publish layout [unit-pair][row] (2 lines/wave, not 32)
// (2) x(t+2) 2-step-lookahead in regs -> embedding HBM latency never in a drain
// (3) fc distributed over 128 threads
// (4) XOR swizzle (c ^= (row&7)<<3) on LDS tiles: 8-way -> ~2-way bank conflicts
#include <hip/hip_runtime.h>

typedef unsigned short u16;
typedef unsigned int   u32;
typedef __attribute__((ext_vector_type(8))) short bf16x8;  // 8 bf16 (4 VGPRs)
typedef __attribute__((ext_vector_type(4))) float f32x4;   // MFMA C/D frag

#define DEVINL static __device__ __forceinline__
#define MFMA __builtin_amdgcn_mfma_f32_16x16x32_bf16
#define SWC(r,c) ((c) ^ (((r) & 7) << 3))   // u16-index swizzle within a row

DEVINL u16 f2bf(float f){ u32 x = __float_as_uint(f); return (u16)((x + 0x7fffu + ((x>>16)&1u)) >> 16); }
DEVINL float bf2f(u16 u){ return __uint_as_float(((u32)u) << 16); }
DEVINL u32 pack2(float a, float b){ return (u32)f2bf(a) | ((u32)f2bf(b) << 16); }
DEVINL float sigm(float x){ return 1.f/(1.f + __expf(-x)); }
DEVINL float tanhs(float x){ float xc = fminf(fmaxf(x,-15.f),15.f); float e = __expf(2.f*xc); return (e-1.f)/(e+1.f); }
DEVINL void g_store(u32* p, u32 v){ __hip_atomic_store(p, v, __ATOMIC_RELAXED, __HIP_MEMORY_SCOPE_AGENT); }
DEVINL u32  g_load(const u32* p){ return __hip_atomic_load(p, __ATOMIC_RELAXED, __HIP_MEMORY_SCOPE_AGENT); }

// ---------------- prep: pack weights to bf16 with row permutation j' = u*4+gate
// matrix order m: 0 eIH_l0, 1 eHH_l0, 2 eIH_l1, 3 eHH_l1, 4 dIH_l0, 5 dHH_l0, 6 dIH_l1, 7 dHH_l1
__global__ void pack_all(const float* __restrict__ eih, const float* __restrict__ ehh,
                         const float* __restrict__ dih, const float* __restrict__ dhh,
                         const float* __restrict__ ebi, const float* __restrict__ ebh,
                         const float* __restrict__ dbi, const float* __restrict__ dbh,
                         u16* __restrict__ wout, float* __restrict__ bout,
                         u32* __restrict__ flags){
  int blk = blockIdx.x, t = threadIdx.x;
  if (blk < 8192){
    int m = blk >> 10, j2 = blk & 1023;
    const float* base = (m < 4) ? ((m & 1) ? ehh : eih) : ((m & 1) ? dhh : dih);
    const float* S = base + (size_t)((m >> 1) & 1) * 262144;  // layer select
    int u = j2 >> 2, g = j2 & 3, j = g*256 + u;
    wout[(size_t)blk*256 + t] = f2bf(S[(size_t)j*256 + t]);
  } else if (blk < 8208){
    int idx = (blk - 8192)*256 + t;             // 0..4095 : [phase][layer][j']
    int phase = idx >> 11, l = (idx >> 10) & 1, j2 = idx & 1023;
    int u = j2 >> 2, g = j2 & 3, j = g*256 + u;
    const float* bi = phase ? dbi : ebi;
    const float* bh = phase ? dbh : ebh;
    bout[idx] = bi[l*1024 + j] + bh[l*1024 + j];
  } else {
    for (int i = t; i < 2048; i += 256) flags[i] = 0u;   // flag reset EVERY call
  }
}

struct SM {
  u16   X[2][16][264];     // x(t) by parity, unit-cols swizzled
  u16   H1t[2][16][264];   // h1 by parity
  u16   H2t[2][16][264];   // h2 by parity
  float fcw[4][256];
  float fcb[4];
  int   tok[63][16];
};

__global__ void __launch_bounds__(512, 2)
lstm_main(const int* __restrict__ src, const float* __restrict__ enc_emb,
          const float* __restrict__ dec_emb, const u16* __restrict__ wpack,
          const float* __restrict__ bpack, const float* __restrict__ fcW,
          const float* __restrict__ fcb, float* __restrict__ out,
          u32* __restrict__ H1, u32* __restrict__ H2, u32* __restrict__ flags)
{
  __shared__ SM sm;
  const int tid  = threadIdx.x;
  const int wv   = tid >> 6;          // wave 0..7
  const int lane = tid & 63;
  const int agrp = lane >> 4;         // k-group
  const int n    = lane & 15;         // batch row
  const int gid  = blockIdx.x & 31;   // batch group (same XCD across slices)
  const int w    = blockIdx.x >> 5;   // column-slice 0..7
  const int wgb0 = gid << 4;
  const int xr   = tid >> 5, xk = (tid & 31) << 3;      // x-gather: row, u16-col
  const int jrow = (w << 7) + (wv << 4) + n;            // permuted gate row j'
  const int uu   = (w << 5) + (wv << 2) + agrp;         // unit owned by lane
  const int up   = (w << 4) + (wv << 1) + (agrp >> 1);  // unit-pair (publish)
  const bool pub = (agrp & 1) == 0;
  // readback ownership: words 4tid..4tid+3 = unit-pair upq, rows nb..nb+3
  const int upq  = tid >> 2, nb = (tid & 3) << 2;

  // ---- prologue staging
  for (int i = tid; i < 1008; i += 512){
    int s = i >> 4, b = i & 15;
    int t = (s < 31) ? (31 - s) : (s - 31);   // enc reversed, then dec forward
    sm.tok[s][b] = src[t*512 + wgb0 + b];
  }
  for (int i = tid; i < 1024; i += 512) ((float*)sm.fcw)[i] = fcW[i];
  if (tid < 4) sm.fcb[tid] = fcb[tid];
  for (int i = tid; i < 2112; i += 512){      // zero parity-0 h tiles
    ((u32*)sm.H1t[0])[i] = 0u;
    ((u32*)sm.H2t[0])[i] = 0u;
  }
  __syncthreads();
  { // x(0) -> X[0]
    int tk = sm.tok[0][xr];
    const float* e = enc_emb + (size_t)tk*256 + xk;
    float4 v0 = *(const float4*)e, v1 = *(const float4*)(e + 4);
    u32* d = (u32*)&sm.X[0][xr][SWC(xr, xk)];
    d[0]=pack2(v0.x,v0.y); d[1]=pack2(v0.z,v0.w); d[2]=pack2(v1.x,v1.y); d[3]=pack2(v1.z,v1.w);
  }
  float4 xc0, xc1;                            // held x(t+1) values
  { // issue x(1)
    int tk = sm.tok[1][xr];
    const float* e = enc_emb + (size_t)tk*256 + xk;
    xc0 = *(const float4*)e; xc1 = *(const float4*)(e + 4);
  }

  // ---- weight-stationary registers: W[2][16] + bias
  bf16x8 W[2][16];
  float4 br[2];
  float  c1 = 0.f, c2s = 0.f;

  auto LOADW_L = [&](int ph, int l){
    const u16* base = wpack + (size_t)ph * 1048576;
    #pragma unroll
    for (int kk = 0; kk < 16; kk++){
      const u16* mp = base + (size_t)((l << 1) + (kk >> 3))*262144
                    + (size_t)jrow*256 + ((kk & 7) << 5) + (agrp << 3);
      W[l][kk] = *(const bf16x8*)mp;
    }
    br[l] = *(const float4*)(bpack + (((ph << 1) + l) << 10) + (uu << 2));
  };
  LOADW_L(0, 0); LOADW_L(0, 1);
  __syncthreads();

  auto step = [&](int t, bool doA){
    const int parR = t & 1, parW = parR ^ 1;
    // ---- shared h1(t-1) fragments (feed l1 k-hi AND l2 k-lo)
    bf16x8 hf[8];
    #pragma unroll
    for (int kk = 0; kk < 8; kk++)
      hf[kk] = *(const bf16x8*)&sm.H1t[parR][n][SWC(n, (kk << 5) + (agrp << 3))];
    // ---- l1(t) over [x(t); h1(t-1)]
    if (doA){
      f32x4 a1 = {0.f,0.f,0.f,0.f};
      #pragma unroll
      for (int kk = 0; kk < 8; kk++){
        bf16x8 bx = *(const bf16x8*)&sm.X[parR][n][SWC(n, (kk << 5) + (agrp << 3))];
        a1 = MFMA(W[0][kk], bx, a1, 0, 0, 0);
      }
      #pragma unroll
      for (int kk = 0; kk < 8; kk++)
        a1 = MFMA(W[0][8 + kk], hf[kk], a1, 0, 0, 0);
      float I = sigm(a1[0] + br[0].x), F = sigm(a1[1] + br[0].y);
      float G = tanhs(a1[2] + br[0].z), O = sigm(a1[3] + br[0].w);
      float cn = F*c1 + I*G; c1 = cn;
      u16 hb = f2bf(O * tanhs(cn));
      u32 other = (u32)__shfl_xor((int)(u32)hb, 16);
      if (pub)
        g_store(H1 + ((size_t)(t & 1)*32 + gid)*2048 + up*16 + n, (u32)hb | (other << 16));
    }
    // ---- l2(t-1) over [h1(t-1); h2(t-2)]
    if (t > 0){
      f32x4 a2 = {0.f,0.f,0.f,0.f};
      #pragma unroll
      for (int kk = 0; kk < 8; kk++)
        a2 = MFMA(W[1][kk], hf[kk], a2, 0, 0, 0);
      #pragma unroll
      for (int kk = 0; kk < 8; kk++){
        bf16x8 b2 = *(const bf16x8*)&sm.H2t[parR][n][SWC(n, (kk << 5) + (agrp << 3))];
        a2 = MFMA(W[1][8 + kk], b2, a2, 0, 0, 0);
      }
      float I = sigm(a2[0] + br[1].x), F = sigm(a2[1] + br[1].y);
      float G = tanhs(a2[2] + br[1].z), O = sigm(a2[3] + br[1].w);
      float cn = F*c2s + I*G; c2s = cn;
      u16 hb = f2bf(O * tanhs(cn));
      u32 other = (u32)__shfl_xor((int)(u32)hb, 16);
      if (pub)
        g_store(H2 + ((size_t)((t - 1) & 1)*32 + gid)*2048 + up*16 + n, (u32)hb | (other << 16));
    }
    __syncthreads();                                           // SA: publishes drained
    if (tid == 0) g_store(&flags[gid*8 + w], (u32)(t + 1));
    if (tid < 64){                                             // wave0: poll 8 flags
      const u32 tgt = (u32)(t + 1);
      const bool mine = lane < 8;
      for (;;){
        u32 v = mine ? g_load(&flags[gid*8 + lane]) : tgt;
        if (__all(v >= tgt)) break;
        __builtin_amdgcn_s_sleep(1);
      }
    }
    __syncthreads();                                           // SC
    { // readback (coalesced global, transposing LDS scatter) + x pipeline
      const int q = tid << 2;
      u32 v0=0,v1=0,v2=0,v3=0, w0=0,w1=0,w2=0,w3=0;
      if (doA){
        const u32* h1r = H1 + ((size_t)(t & 1)*32 + gid)*2048;
        v0 = g_load(h1r+q); v1 = g_load(h1r+q+1); v2 = g_load(h1r+q+2); v3 = g_load(h1r+q+3);
      }
      if (t > 0){
        const u32* h2r = H2 + ((size_t)((t - 1) & 1)*32 + gid)*2048;
        w0 = g_load(h2r+q); w1 = g_load(h2r+q+1); w2 = g_load(h2r+q+2); w3 = g_load(h2r+q+3);
      }
      // issue x(t+2) AFTER h loads (younger -> not waited by h consumption)
      float4 xn0, xn1;
      const bool issx = doA && (t + 2) < 63;
      if (issx){
        int tk = sm.tok[t+2][xr];
        const float* e = ((t+2) < 31 ? enc_emb : dec_emb) + (size_t)tk*256 + xk;
        xn0 = *(const float4*)e; xn1 = *(const float4*)(e + 4);
      }
      if (doA){
        *(u32*)&sm.H1t[parW][nb+0][SWC(nb+0, upq << 1)] = v0;
        *(u32*)&sm.H1t[parW][nb+1][SWC(nb+1, upq << 1)] = v1;
        *(u32*)&sm.H1t[parW][nb+2][SWC(nb+2, upq << 1)] = v2;
        *(u32*)&sm.H1t[parW][nb+3][SWC(nb+3, upq << 1)] = v3;
      }
      if (t > 0){
        *(u32*)&sm.H2t[parW][nb+0][SWC(nb+0, upq << 1)] = w0;
        *(u32*)&sm.H2t[parW][nb+1][SWC(nb+1, upq << 1)] = w1;
        *(u32*)&sm.H2t[parW][nb+2][SWC(nb+2, upq << 1)] = w2;
        *(u32*)&sm.H2t[parW][nb+3][SWC(nb+3, upq << 1)] = w3;
      }
      if (doA && (t + 1) < 63){                 // consume held x(t+1) -> X[parW]
        u32* d = (u32*)&sm.X[parW][xr][SWC(xr, xk)];
        d[0]=pack2(xc0.x,xc0.y); d[1]=pack2(xc0.z,xc0.w);
        d[2]=pack2(xc1.x,xc1.y); d[3]=pack2(xc1.z,xc1.w);
      }
      if (issx){ xc0 = xn0; xc1 = xn1; }
    }
    __syncthreads();                                           // SD
    // ---- fc + log_softmax on h2(t-1) in H2t[parW]; 128 threads, overlaps next step
    if (t >= 32 && tid < 128){
      const int b = (w << 1) + (tid >> 6), v = (tid >> 4) & 3, q16 = tid & 15;
      const u16* hA = &sm.H2t[parW][b][SWC(b,  q16 << 4)];
      const u16* hB = &sm.H2t[parW][b][SWC(b, (q16 << 4) + 8)];
      const float* wr = &sm.fcw[v][q16 << 4];
      bf16x8 h0 = *(const bf16x8*)hA, h1v = *(const bf16x8*)hB;
      float s = 0.f;
      #pragma unroll
      for (int e = 0; e < 8; e++){
        s += bf2f((u16)h0[e]) * wr[e];
        s += bf2f((u16)h1v[e]) * wr[8 + e];
      }
      s += __shfl_xor(s, 1); s += __shfl_xor(s, 2);
      s += __shfl_xor(s, 4); s += __shfl_xor(s, 8);
      s += sm.fcb[v];
      float m = fmaxf(s, __shfl_xor(s, 16)); m = fmaxf(m, __shfl_xor(m, 32));
      float e_ = __expf(s - m);
      float es = e_ + __shfl_xor(e_, 16); es += __shfl_xor(es, 32);
      if (q16 == 0)
        out[((size_t)(t - 32)*512 + wgb0 + b)*4 + v] = s - m - __logf(es);
    }
  };

  for (int t = 0; t <= 30; ++t) step(t, true);
  LOADW_L(1, 0);            // dec W1 (first used by l1(31)); l2(30) still enc W2
  step(31, true);
  LOADW_L(1, 1);            // dec W2 (first used by l2(31) at step 32)
  for (int t = 32; t <= 62; ++t) step(t, true);
  step(63, false);          // tail: l2(62) + fc(62) -> out row 31
}

extern "C" void kernel_launch(void* const* d_in, const int* in_sizes, int n_in,
                              void* d_out, int out_size, void* d_ws, size_t ws_size,
                              hipStream_t stream){
  const int*   src     = (const int*)  d_in[0];
  const float* enc_emb = (const float*)d_in[2];
  const float* enc_Wih = (const float*)d_in[3];
  const float* enc_Whh = (const float*)d_in[4];
  const float* enc_bih = (const float*)d_in[5];
  const float* enc_bhh = (const float*)d_in[6];
  const float* dec_emb = (const float*)d_in[7];
  const float* dec_Wih = (const float*)d_in[8];
  const float* dec_Whh = (const float*)d_in[9];
  const float* dec_bih = (const float*)d_in[10];
  const float* dec_bhh = (const float*)d_in[11];
  const float* fcW     = (const float*)d_in[12];
  const float* fcb     = (const float*)d_in[13];
  float* out = (float*)d_out;
  (void)in_sizes; (void)n_in; (void)out_size; (void)ws_size;

  // ws: wpack 4MB | bpack 16KB | H1 512KB (2-parity) | H2 512KB | flags 8KB
  u16*   wpack = (u16*)d_ws;
  float* bpack = (float*)((char*)d_ws + 4194304);
  u32*   H1    = (u32*)((char*)d_ws + 4194304 + 16384);
  u32*   H2    = (u32*)((char*)d_ws + 4194304 + 16384 + 524288);
  u32*   flags = (u32*)((char*)d_ws + 4194304 + 16384 + 1048576);

  pack_all<<<8209, 256, 0, stream>>>(enc_Wih, enc_Whh, dec_Wih, dec_Whh,
                                     enc_bih, enc_bhh, dec_bih, dec_bhh,
                                     wpack, bpack, flags);
  lstm_main<<<256, 512, 0, stream>>>(src, enc_emb, dec_emb, wpack, bpack,
                                     fcW, fcb, out, H1, H2, flags);
}

// Round 8
// 258.479 us; speedup vs baseline: 3.3324x; 2.6686x over previous
//
// Round 8: wave-specialized layers. Waves 0-3 = layer1 (2 gate-tiles, W1 in 128
// VGPR), waves 4-7 = layer2. Each B-frag read feeds 2 MFMAs -> LDS read volume
// halves (256->128 KB/CU/step). Skeleton = round 4 (best, 489us): row-major H,
// scattered publish, clean b128 readback, 3 barriers/step, wave0 flag poll.
// NO LDS swizzle (r7's tripled conflicts). 128-thread fc (r7, kept).
#include <hip/hip_runtime.h>

typedef unsigned short u16;
typedef unsigned int   u32;
typedef __attribute__((ext_vector_type(8))) short bf16x8;  // 8 bf16 (4 VGPRs)
typedef __attribute__((ext_vector_type(4))) float f32x4;   // MFMA C/D frag

#define DEVINL static __device__ __forceinline__
#define MFMA __builtin_amdgcn_mfma_f32_16x16x32_bf16

DEVINL u16 f2bf(float f){ u32 x = __float_as_uint(f); return (u16)((x + 0x7fffu + ((x>>16)&1u)) >> 16); }
DEVINL float bf2f(u16 u){ return __uint_as_float(((u32)u) << 16); }
DEVINL u32 pack2(float a, float b){ return (u32)f2bf(a) | ((u32)f2bf(b) << 16); }
DEVINL float sigm(float x){ return 1.f/(1.f + __expf(-x)); }
DEVINL float tanhs(float x){ float xc = fminf(fmaxf(x,-15.f),15.f); float e = __expf(2.f*xc); return (e-1.f)/(e+1.f); }
DEVINL void g_store(u32* p, u32 v){ __hip_atomic_store(p, v, __ATOMIC_RELAXED, __HIP_MEMORY_SCOPE_AGENT); }
DEVINL u32  g_load(const u32* p){ return __hip_atomic_load(p, __ATOMIC_RELAXED, __HIP_MEMORY_SCOPE_AGENT); }

// ---------------- prep: pack weights to bf16 with row permutation j' = u*4+gate
// matrix order m: 0 eIH_l0, 1 eHH_l0, 2 eIH_l1, 3 eHH_l1, 4 dIH_l0, 5 dHH_l0, 6 dIH_l1, 7 dHH_l1
__global__ void pack_all(const float* __restrict__ eih, const float* __restrict__ ehh,
                         const float* __restrict__ dih, const float* __restrict__ dhh,
                         const float* __restrict__ ebi, const float* __restrict__ ebh,
                         const float* __restrict__ dbi, const float* __restrict__ dbh,
                         u16* __restrict__ wout, float* __restrict__ bout,
                         u32* __restrict__ flags){
  int blk = blockIdx.x, t = threadIdx.x;
  if (blk < 8192){
    int m = blk >> 10, j2 = blk & 1023;
    const float* base = (m < 4) ? ((m & 1) ? ehh : eih) : ((m & 1) ? dhh : dih);
    const float* S = base + (size_t)((m >> 1) & 1) * 262144;  // layer select
    int u = j2 >> 2, g = j2 & 3, j = g*256 + u;
    wout[(size_t)blk*256 + t] = f2bf(S[(size_t)j*256 + t]);
  } else if (blk < 8208){
    int idx = (blk - 8192)*256 + t;             // 0..4095 : [phase][layer][j']
    int phase = idx >> 11, l = (idx >> 10) & 1, j2 = idx & 1023;
    int u = j2 >> 2, g = j2 & 3, j = g*256 + u;
    const float* bi = phase ? dbi : ebi;
    const float* bh = phase ? dbh : ebh;
    bout[idx] = bi[l*1024 + j] + bh[l*1024 + j];
  } else {
    for (int i = t; i < 2048; i += 256) flags[i] = 0u;   // flag reset EVERY call
  }
}

struct SM {
  u16   X[16][264];       // x(t), row stride 264 u16 (132 words ≡ 4 mod 32)
  u16   H1t[16][264];     // h1(t-1)
  u16   H2t[16][264];     // h2(t-2) (pre-readback) / h2(t-1) (post)
  float fcw[4][256];
  float fcb[4];
  int   tok[63][16];
};

__global__ void __launch_bounds__(512, 2)
lstm_main(const int* __restrict__ src, const float* __restrict__ enc_emb,
          const float* __restrict__ dec_emb, const u16* __restrict__ wpack,
          const float* __restrict__ bpack, const float* __restrict__ fcW,
          const float* __restrict__ fcb, float* __restrict__ out,
          u32* __restrict__ H1, u32* __restrict__ H2, u32* __restrict__ flags)
{
  __shared__ SM sm;
  const int tid  = threadIdx.x;
  const int wv   = tid >> 6;          // wave 0..7
  const int lane = tid & 63;
  const int agrp = lane >> 4;         // k-group
  const int n    = lane & 15;         // batch row
  const int gid  = blockIdx.x & 31;   // batch group (same XCD across slices)
  const int w    = blockIdx.x >> 5;   // column-slice 0..7
  const int wgb0 = gid << 4;
  const int xr   = tid >> 5, xk = (tid & 31) << 3;     // x-gather: row, u16-col
  const int myl  = wv >> 2;           // 0: layer1-wave, 1: layer2-wave
  const int wq   = wv & 3;            // quarter within role
  const bool pub = (agrp & 1) == 0;
  const int jrow0 = (w << 7) + (wq << 5) + n;          // gate row j', tile ct=0
  const int jrow1 = jrow0 + 16;                        // tile ct=1
  const int uu0   = (w << 5) + (wq << 3) + agrp;       // unit, tile ct=0
  const int uu1   = uu0 + 4;
  const int pw0   = (w << 4) + (wq << 2) + (agrp >> 1);// u32 word, tile ct=0
  const int pw1   = pw0 + 2;

  // ---- prologue staging
  for (int i = tid; i < 1008; i += 512){
    int s = i >> 4, b = i & 15;
    int t = (s < 31) ? (31 - s) : (s - 31);   // enc reversed, then dec forward
    sm.tok[s][b] = src[t*512 + wgb0 + b];
  }
  for (int i = tid; i < 1024; i += 512) ((float*)sm.fcw)[i] = fcW[i];
  if (tid < 4) sm.fcb[tid] = fcb[tid];
  for (int i = tid; i < 2112; i += 512){      // zero h tiles
    ((u32*)sm.H1t)[i] = 0u;
    ((u32*)sm.H2t)[i] = 0u;
  }
  __syncthreads();
  { // x(0) -> X
    int tk = sm.tok[0][xr];
    const float* e = enc_emb + (size_t)tk*256 + xk;
    float4 v0 = *(const float4*)e, v1 = *(const float4*)(e + 4);
    u32* d = (u32*)&sm.X[xr][xk];
    d[0]=pack2(v0.x,v0.y); d[1]=pack2(v0.z,v0.w); d[2]=pack2(v1.x,v1.y); d[3]=pack2(v1.z,v1.w);
  }

  // ---- weight-stationary: my layer's 2 gate-tiles, W[2][16] = 128 VGPR
  bf16x8 W[2][16];
  float4 br[2];
  float  cst[2] = {0.f, 0.f};

  auto LOADW = [&](int ph){
    const u16* base = wpack + (size_t)ph*1048576 + (size_t)myl*524288;
    #pragma unroll
    for (int kk = 0; kk < 16; kk++){
      const size_t moff = (size_t)(kk >> 3)*262144 + ((kk & 7) << 5) + (agrp << 3);
      W[0][kk] = *(const bf16x8*)(base + moff + (size_t)jrow0*256);
      W[1][kk] = *(const bf16x8*)(base + moff + (size_t)jrow1*256);
    }
    br[0] = *(const float4*)(bpack + (((ph << 1) + myl) << 10) + (uu0 << 2));
    br[1] = *(const float4*)(bpack + (((ph << 1) + myl) << 10) + (uu1 << 2));
  };
  LOADW(0);
  __syncthreads();

  auto step = [&](int t){
    // ---- issue x(t+1) loads early (drain hidden behind compute, as r4)
    const bool hasx = (t + 1) < 63;
    float4 xv0, xv1;
    if (hasx){
      int tk = sm.tok[t+1][xr];
      const float* e = ((t+1) < 31 ? enc_emb : dec_emb) + (size_t)tk*256 + xk;
      xv0 = *(const float4*)e; xv1 = *(const float4*)(e + 4);
    }
    // ---- compute my layer: l1(t) for waves 0-3, l2(t-1) for waves 4-7
    const bool active = myl ? (t > 0) : (t < 63);
    if (active){
      const u16 (*loT)[264] = myl ? sm.H1t : sm.X;    // l1: x(t)   ; l2: h1(t-1)
      const u16 (*hiT)[264] = myl ? sm.H2t : sm.H1t;  // l1: h1(t-1); l2: h2(t-2)
      f32x4 a0 = {0.f,0.f,0.f,0.f}, a1 = {0.f,0.f,0.f,0.f};
      #pragma unroll
      for (int kk = 0; kk < 8; kk++){
        bf16x8 b = *(const bf16x8*)&loT[n][(kk << 5) + (agrp << 3)];
        a0 = MFMA(W[0][kk], b, a0, 0, 0, 0);
        a1 = MFMA(W[1][kk], b, a1, 0, 0, 0);
      }
      #pragma unroll
      for (int kk = 0; kk < 8; kk++){
        bf16x8 b = *(const bf16x8*)&hiT[n][(kk << 5) + (agrp << 3)];
        a0 = MFMA(W[8 >> 3 ? 0 : 0][8 + kk], b, a0, 0, 0, 0);
        a1 = MFMA(W[1][8 + kk], b, a1, 0, 0, 0);
      }
      // gates for both tiles; publish h slices (r4 row-major H layout)
      float I0 = sigm(a0[0] + br[0].x), F0 = sigm(a0[1] + br[0].y);
      float G0 = tanhs(a0[2] + br[0].z), O0 = sigm(a0[3] + br[0].w);
      float cn0 = F0*cst[0] + I0*G0; cst[0] = cn0;
      u16 h0 = f2bf(O0 * tanhs(cn0));
      float I1 = sigm(a1[0] + br[1].x), F1 = sigm(a1[1] + br[1].y);
      float G1 = tanhs(a1[2] + br[1].z), O1 = sigm(a1[3] + br[1].w);
      float cn1 = F1*cst[1] + I1*G1; cst[1] = cn1;
      u16 h1b = f2bf(O1 * tanhs(cn1));
      u32 o0 = (u32)__shfl_xor((int)(u32)h0, 16);
      u32 o1 = (u32)__shfl_xor((int)(u32)h1b, 16);
      const int ppar = myl ? ((t + 1) & 1) : (t & 1);   // l2 publishes h2(t-1)
      u32* Hp = (myl ? H2 : H1) + ((size_t)ppar*32 + gid)*2048 + n*128;
      if (pub){
        g_store(Hp + pw0, (u32)h0 | (o0 << 16));
        g_store(Hp + pw1, (u32)h1b | (o1 << 16));
      }
    }
    __syncthreads();                                           // SA: stores drained
    if (tid == 0) g_store(&flags[gid*8 + w], (u32)(t + 1));
    if (hasx){                                                 // x(t+1) -> X
      u32* d = (u32*)&sm.X[xr][xk];
      d[0]=pack2(xv0.x,xv0.y); d[1]=pack2(xv0.z,xv0.w);
      d[2]=pack2(xv1.x,xv1.y); d[3]=pack2(xv1.z,xv1.w);
    }
    if (tid < 64){                                             // wave0: poll 8 flags
      const u32 tgt = (u32)(t + 1);
      const bool mine = lane < 8;
      for (;;){
        u32 v = mine ? g_load(&flags[gid*8 + lane]) : tgt;
        if (__all(v >= tgt)) break;
        __builtin_amdgcn_s_sleep(1);
      }
    }
    __syncthreads();                                           // SC
    { // readback: h1(t) -> H1t, h2(t-1) -> H2t  (contiguous 16B per thread)
      const int q = tid << 2, r = tid >> 5, p = q & 127;
      if (t < 63){
        const u32* h1r = H1 + ((size_t)(t & 1)*32 + gid)*2048;
        u32 v0 = g_load(h1r+q), v1 = g_load(h1r+q+1), v2 = g_load(h1r+q+2), v3 = g_load(h1r+q+3);
        u32* d1 = (u32*)&sm.H1t[r][p << 1];
        d1[0]=v0; d1[1]=v1; d1[2]=v2; d1[3]=v3;
      }
      if (t > 0){
        const u32* h2r = H2 + ((size_t)((t - 1) & 1)*32 + gid)*2048;
        u32 w0 = g_load(h2r+q), w1 = g_load(h2r+q+1), w2 = g_load(h2r+q+2), w3 = g_load(h2r+q+3);
        u32* d2 = (u32*)&sm.H2t[r][p << 1];
        d2[0]=w0; d2[1]=w1; d2[2]=w2; d2[3]=w3;
      }
    }
    __syncthreads();                                           // SD
    // ---- fc + log_softmax on h2(t-1) in H2t; 128 threads, overlaps next step
    if (t >= 32 && tid < 128){
      const int b = (w << 1) + (tid >> 6), v = (tid >> 4) & 3, q16 = tid & 15;
      const u16* hrow = &sm.H2t[b][q16 << 4];
      const float* wr = &sm.fcw[v][q16 << 4];
      bf16x8 h0 = *(const bf16x8*)hrow, h1v = *(const bf16x8*)(hrow + 8);
      float s = 0.f;
      #pragma unroll
      for (int e = 0; e < 8; e++){
        s += bf2f((u16)h0[e]) * wr[e];
        s += bf2f((u16)h1v[e]) * wr[8 + e];
      }
      s += __shfl_xor(s, 1); s += __shfl_xor(s, 2);
      s += __shfl_xor(s, 4); s += __shfl_xor(s, 8);
      s += sm.fcb[v];
      float m = fmaxf(s, __shfl_xor(s, 16)); m = fmaxf(m, __shfl_xor(m, 32));
      float e_ = __expf(s - m);
      float es = e_ + __shfl_xor(e_, 16); es += __shfl_xor(es, 32);
      if (q16 == 0)
        out[((size_t)(t - 32)*512 + wgb0 + b)*4 + v] = s - m - __logf(es);
    }
  };

  for (int t = 0; t <= 30; ++t) step(t);
  if (myl == 0) LOADW(1);   // dec W1 (first used by l1(31)); l2(30) still enc W2
  step(31);
  if (myl == 1) LOADW(1);   // dec W2 (first used computing l2(31) at step 32)
  for (int t = 32; t <= 62; ++t) step(t);
  step(63);                 // tail: l2(62) + fc(62) -> out row 31
}

extern "C" void kernel_launch(void* const* d_in, const int* in_sizes, int n_in,
                              void* d_out, int out_size, void* d_ws, size_t ws_size,
                              hipStream_t stream){
  const int*   src     = (const int*)  d_in[0];
  const float* enc_emb = (const float*)d_in[2];
  const float* enc_Wih = (const float*)d_in[3];
  const float* enc_Whh = (const float*)d_in[4];
  const float* enc_bih = (const float*)d_in[5];
  const float* enc_bhh = (const float*)d_in[6];
  const float* dec_emb = (const float*)d_in[7];
  const float* dec_Wih = (const float*)d_in[8];
  const float* dec_Whh = (const float*)d_in[9];
  const float* dec_bih = (const float*)d_in[10];
  const float* dec_bhh = (const float*)d_in[11];
  const float* fcW     = (const float*)d_in[12];
  const float* fcb     = (const float*)d_in[13];
  float* out = (float*)d_out;
  (void)in_sizes; (void)n_in; (void)out_size; (void)ws_size;

  // ws: wpack 4MB | bpack 16KB | H1 512KB (2-parity) | H2 512KB | flags 8KB
  u16*   wpack = (u16*)d_ws;
  float* bpack = (float*)((char*)d_ws + 4194304);
  u32*   H1    = (u32*)((char*)d_ws + 4194304 + 16384);
  u32*   H2    = (u32*)((char*)d_ws + 4194304 + 16384 + 524288);
  u32*   flags = (u32*)((char*)d_ws + 4194304 + 16384 + 1048576);

  pack_all<<<8209, 256, 0, stream>>>(enc_Wih, enc_Whh, dec_Wih, dec_Whh,
                                     enc_bih, enc_bhh, dec_bih, dec_bhh,
                                     wpack, bpack, flags);
  lstm_main<<<256, 512, 0, stream>>>(src, enc_emb, dec_emb, wpack, bpack,
                                     fcW, fcb, out, H1, H2, flags);
}